// Round 3
// baseline (650.667 us; speedup 1.0000x reference)
//
#include <hip/hip_runtime.h>

// 2-layer LSTM (H=12), B=8192, T=1024 + 64 free-running steps.
// R9: PRODUCER/CONSUMER WAVE PIPELINE.
// Structural fact: cell1(t) depends only on {x(t), h1(t-1), c1(t-1)} — NOT h2.
// So cell1 and cell2 form a feed-forward pipeline:
//   wave 0: full cell1 chain, pushes h1(t) into an LDS FIFO (slot t%8)
//   wave 1: full cell2 chain + y, runs LAG=4 steps behind, prefetches h1
//           one iteration early (ds_read latency hidden under compute)
// Each wave's recurrent state (c, h, B-fragment) stays in registers; the FIFO
// is one-directional so no LDS round-trip sits on the recurrence critical
// path (R6's failure). 1024 waves = one per SIMD chip-wide (was 512 = half
// the SIMDs idle, each saturated at ~70% issue with 42 trans-ops/step).
//
// Lane alignment (R7 k-order, harness-verified): wave0 lane (g,n) computes
// h1 units {4j+g} for element n — exactly wave1's B-fragment slots j=0..2 at
// the same lane. FIFO transfer = 8 B/lane, same-lane, conflict-free.
// FIFO safety: writer slot k, reader prefetches slot k-3 (3 barriers behind),
// overwrite distance 8 (5 barriers margin). One __syncthreads per step.
//
// Fragment maps (gfx950, HW-verified):
//   A[m=lane&15][k=8*(lane>>4)+j], B[k=8*(lane>>4)+j][n=lane&15],
//   D[row=4*(lane>>4)+reg][col=lane&15].

typedef _Float16 v8h  __attribute__((ext_vector_type(8)));
typedef _Float16 v4h  __attribute__((ext_vector_type(4)));
typedef float    v4f  __attribute__((ext_vector_type(4)));

constexpr int T   = 1024;
constexpr int FUT = 64;
constexpr int TT  = T + FUT;   // 1088
constexpr int B   = 8192;

static __device__ __forceinline__ float fexp2(float x){ return __builtin_amdgcn_exp2f(x); }
static __device__ __forceinline__ float frcp (float x){ return __builtin_amdgcn_rcpf(x); }

__global__ __launch_bounds__(128) void lstm_pipe_kernel(
    const float* __restrict__ input,
    const float* __restrict__ w_ih1, const float* __restrict__ w_hh1,
    const float* __restrict__ b_ih1, const float* __restrict__ b_hh1,
    const float* __restrict__ w_ih2, const float* __restrict__ w_hh2,
    const float* __restrict__ b_ih2, const float* __restrict__ b_hh2,
    const float* __restrict__ w_lin, const float* __restrict__ b_lin,
    float* __restrict__ out)
{
  const int tid  = threadIdx.x;
  const int wid  = tid >> 6;        // 0 = cell1 producer, 1 = cell2 consumer
  const int lane = tid & 63;
  const int g    = lane >> 4;       // unit residue group
  const int n    = lane & 15;       // element column
  const int e0   = blockIdx.x * 16;

  const float L2E = 1.4426950408889634f;
  const float sc[4] = { -L2E, -L2E, 2.0f * L2E, -L2E };  // i,f,g,o prescale
  const float TWO_L2E = 2.885390081777927f;

  // ---- per-wave fragment set (unified registers: wave0=cell1, wave1=cell2)
  v8h Aw[3]; v4f Cw[3];
  float wix[3][4];   // wave0: prescaled w_ih1 (x weights); wave1: unused
  float wl[3] = {0,0,0};
  {
    const int q = n & 3;
    #pragma unroll
    for (int c = 0; c < 3; ++c) {
      const int v   = 4 * c + (n >> 2);
      const int row = q * 12 + v;
      v8h a = {0,0,0,0,0,0,0,0};
      if (wid == 0) {
        #pragma unroll
        for (int j = 0; j < 3; ++j)
          a[j] = (_Float16)(sc[q] * w_hh1[row * 12 + (4 * j + g)]);
      } else {
        #pragma unroll
        for (int j = 0; j < 3; ++j) {
          const int u = 4 * j + g;
          a[j]     = (_Float16)(sc[q] * w_ih2[row * 12 + u]);  // h1 cols
          a[j + 4] = (_Float16)(sc[q] * w_hh2[row * 12 + u]);  // h2 cols
        }
      }
      Aw[c] = a;
    }
    #pragma unroll
    for (int c = 0; c < 3; ++c) {
      const int v = 4 * c + g;
      #pragma unroll
      for (int r = 0; r < 4; ++r) {
        if (wid == 0) {
          Cw[c][r]  = sc[r] * (b_ih1[r * 12 + v] + b_hh1[r * 12 + v]);
          wix[c][r] = sc[r] * w_ih1[r * 12 + v];
        } else {
          Cw[c][r]  = sc[r] * (b_ih2[r * 12 + v] + b_hh2[r * 12 + v]);
          wix[c][r] = 0.0f;
        }
      }
      if (wid == 1) wl[c] = w_lin[v];
    }
  }
  const float blin = b_lin[0];

  // ---- LDS FIFO: 8 slots x 64 lanes x 8 B = 4 KiB ------------------------
  __shared__ v4h fifo[8][64];

  // ---- per-wave recurrent state (registers) ------------------------------
  float csw[3] = {0,0,0};
  v8h  Bw = {0,0,0,0,0,0,0,0};
  v4h  pf = {0,0,0,0};

  const float* xrow   = input + (size_t)(e0 + n) * T;
  float*       yrow   = out   + (size_t)(e0 + n) * TT;
  const bool   ystore = (wid == 1) && (g == 3);
  const float  xl     = (wid == 0) ? xrow[T - 1] : 0.0f;

  auto act3 = [&](const float (&G)[3][4], float (&h)[3]) {
    float Ai[3], Af[3], Eg[3], Ao[3];
    #pragma unroll
    for (int c = 0; c < 3; ++c) Ai[c] = fexp2(G[c][0]);
    #pragma unroll
    for (int c = 0; c < 3; ++c) Af[c] = fexp2(G[c][1]);
    #pragma unroll
    for (int c = 0; c < 3; ++c) Eg[c] = fexp2(G[c][2]);
    #pragma unroll
    for (int c = 0; c < 3; ++c) Ao[c] = fexp2(G[c][3]);
    float pfx[3], P[3], R[3], Nn[3], Ec[3], R2[3];
    #pragma unroll
    for (int c = 0; c < 3; ++c) { pfx[c] = 1.0f + Af[c]; P[c] = (1.0f + Ai[c]) * (1.0f + Eg[c]); }
    #pragma unroll
    for (int c = 0; c < 3; ++c) R[c]  = frcp(P[c] * pfx[c]);
    #pragma unroll
    for (int c = 0; c < 3; ++c) Nn[c] = fmaf(csw[c], P[c], (Eg[c] - 1.0f) * pfx[c]);
    #pragma unroll
    for (int c = 0; c < 3; ++c) csw[c] = Nn[c] * R[c];
    #pragma unroll
    for (int c = 0; c < 3; ++c) Ec[c] = fexp2(TWO_L2E * csw[c]);
    #pragma unroll
    for (int c = 0; c < 3; ++c) R2[c] = frcp((1.0f + Ao[c]) * (1.0f + Ec[c]));
    #pragma unroll
    for (int c = 0; c < 3; ++c) h[c] = (Ec[c] - 1.0f) * R2[c];
  };

  // wave 0: one cell1 step at time k; push h1(k) into FIFO slot k%8
  auto subA = [&](int k, float x) {
    if (k < TT) {
      v4f D0 = __builtin_amdgcn_mfma_f32_16x16x32_f16(Aw[0], Bw, Cw[0], 0, 0, 0);
      v4f D1 = __builtin_amdgcn_mfma_f32_16x16x32_f16(Aw[1], Bw, Cw[1], 0, 0, 0);
      v4f D2 = __builtin_amdgcn_mfma_f32_16x16x32_f16(Aw[2], Bw, Cw[2], 0, 0, 0);
      float G[3][4], h[3];
      #pragma unroll
      for (int r = 0; r < 4; ++r) G[0][r] = fmaf(wix[0][r], x, D0[r]);
      #pragma unroll
      for (int r = 0; r < 4; ++r) G[1][r] = fmaf(wix[1][r], x, D1[r]);
      #pragma unroll
      for (int r = 0; r < 4; ++r) G[2][r] = fmaf(wix[2][r], x, D2[r]);
      act3(G, h);
      v4h pk;
      pk[0] = (_Float16)h[0]; pk[1] = (_Float16)h[1];
      pk[2] = (_Float16)h[2]; pk[3] = (_Float16)0.0f;
      fifo[k & 7][lane] = pk;
      Bw[0] = pk[0]; Bw[1] = pk[1]; Bw[2] = pk[2];
    }
  };

  // wave 1: prefetch h1 slot (k-3) for NEXT iter; compute cell2 step t=k-4
  auto subB = [&](int k, float& ybs) {
    v4h pfn = pf;
    const bool dp = (k >= 3) && (k <= TT + 2);
    if (dp) pfn = fifo[(k - 3) & 7][lane];
    if (k >= 4) {
      Bw[0] = pf[0]; Bw[1] = pf[1]; Bw[2] = pf[2]; Bw[3] = pf[3];
      v4f D0 = __builtin_amdgcn_mfma_f32_16x16x32_f16(Aw[0], Bw, Cw[0], 0, 0, 0);
      v4f D1 = __builtin_amdgcn_mfma_f32_16x16x32_f16(Aw[1], Bw, Cw[1], 0, 0, 0);
      v4f D2 = __builtin_amdgcn_mfma_f32_16x16x32_f16(Aw[2], Bw, Cw[2], 0, 0, 0);
      float G[3][4], h[3];
      #pragma unroll
      for (int r = 0; r < 4; ++r) G[0][r] = D0[r];
      #pragma unroll
      for (int r = 0; r < 4; ++r) G[1][r] = D1[r];
      #pragma unroll
      for (int r = 0; r < 4; ++r) G[2][r] = D2[r];
      act3(G, h);
      Bw[4] = (_Float16)h[0]; Bw[5] = (_Float16)h[1]; Bw[6] = (_Float16)h[2];
      float yp = h[0] * wl[0];
      yp = fmaf(h[1], wl[1], yp);
      yp = fmaf(h[2], wl[2], yp);
      yp += __shfl_xor(yp, 16);
      yp += __shfl_xor(yp, 32);
      ybs = yp + blin;
    }
    pf = pfn;
  };

  float4 xv = make_float4(0.f, 0.f, 0.f, 0.f);
  if (wid == 0) xv = *reinterpret_cast<const float4*>(xrow);
  float yb0 = 0.f, yb1 = 0.f, yb2 = 0.f, yb3 = 0.f;

  for (int kb = 0; kb < TT + 4; kb += 4) {
    float4 xn = xv;
    if (wid == 0) {
      if (kb + 4 < T) xn = *reinterpret_cast<const float4*>(xrow + kb + 4);
      else            xn = make_float4(xl, xl, xl, xl);
    }
    if (wid == 0) subA(kb + 0, xv.x);
    __syncthreads();
    if (wid == 1) subB(kb + 0, yb0);

    if (wid == 0) subA(kb + 1, xv.y);
    __syncthreads();
    if (wid == 1) subB(kb + 1, yb1);

    if (wid == 0) subA(kb + 2, xv.z);
    __syncthreads();
    if (wid == 1) subB(kb + 2, yb2);

    if (wid == 0) subA(kb + 3, xv.w);
    __syncthreads();
    if (wid == 1) subB(kb + 3, yb3);

    if (ystore && kb >= 4)
      *reinterpret_cast<float4*>(yrow + kb - 4) = make_float4(yb0, yb1, yb2, yb3);
    xv = xn;
  }
}

extern "C" void kernel_launch(void* const* d_in, const int* in_sizes, int n_in,
                              void* d_out, int out_size, void* d_ws, size_t ws_size,
                              hipStream_t stream) {
  const float* input = (const float*)d_in[0];
  const float* w_ih1 = (const float*)d_in[2];
  const float* w_hh1 = (const float*)d_in[3];
  const float* b_ih1 = (const float*)d_in[4];
  const float* b_hh1 = (const float*)d_in[5];
  const float* w_ih2 = (const float*)d_in[6];
  const float* w_hh2 = (const float*)d_in[7];
  const float* b_ih2 = (const float*)d_in[8];
  const float* b_hh2 = (const float*)d_in[9];
  const float* w_lin = (const float*)d_in[10];
  const float* b_lin = (const float*)d_in[11];
  float* out = (float*)d_out;

  dim3 grid(B / 16);   // 512 blocks x 2 waves = 1024 waves = 1 per SIMD
  dim3 block(128);
  hipLaunchKernelGGL(lstm_pipe_kernel, grid, block, 0, stream,
                     input, w_ih1, w_hh1, b_ih1, b_hh1,
                     w_ih2, w_hh2, b_ih2, b_hh2, w_lin, b_lin, out);
}

// Round 4
// 575.048 us; speedup vs baseline: 1.1315x; 1.1315x over previous
//
#include <hip/hip_runtime.h>

// 2-layer LSTM (H=12), B=8192, T=1024 + 64 free-running steps.
// R10: SINGLE-WAVE, CELL2 SKEWED ONE STEP BEHIND CELL1.
// R7-R9 post-mortem: every structure lands ~1200-1300 cy/step because the two
// cell chains execute SERIALLY (cell2(t) needs h1(t) within the step; compiler
// does not pipeline across the step boundary; a 2-wave split just moves the
// serialization to barriers). Fix is structural: compute cell1(t) and
// cell2(t-1) in the same substep. cell2(t-1) consumes h1(t-1) and h2(t-2) —
// so ONE shared B fragment {h1(t-1), h2(t-2)} feeds all 6 MFMAs issued at the
// top of the substep, and the two act chains run concurrently between packs.
// Step interval: C_cell1 + C_cell2  ->  max(C_cell1, C_cell2).
// Also removes __shfl_xor from the loop (LDS-pipe + lgkm waits): per-lane
// y-partials go to a 4KB LDS buffer (fire-and-forget ds_write), reduced and
// float4-stored once per 16 steps.
// Semantics identical to R7 (same h vintages, same f16 crossing points).
//
// Layout (harness-verified):
//   Row order R = 4*v + q; chunk c row (lane&15) -> v=4c+(m>>2), q=m&3.
//   K order k = 8*(u%4) + (u/4); B slot (g,j<3) = h_{4j+g} -> lane-local
//   D->B handoff; pads at j=3,7. Cell1 A zeros on h2 slots.
// Fragment maps (gfx950, HW-verified):
//   A[m=lane&15][k=8*(lane>>4)+j], B[k=8*(lane>>4)+j][n=lane&15],
//   D[row=4*(lane>>4)+reg][col=lane&15].

typedef _Float16 v8h  __attribute__((ext_vector_type(8)));
typedef float    v4f  __attribute__((ext_vector_type(4)));

constexpr int T   = 1024;
constexpr int FUT = 64;
constexpr int TT  = T + FUT;   // 1088 = 68 * 16 (exact, no flush tail)
constexpr int B   = 8192;

static __device__ __forceinline__ float fexp2(float x){ return __builtin_amdgcn_exp2f(x); }
static __device__ __forceinline__ float frcp (float x){ return __builtin_amdgcn_rcpf(x); }

__global__ __launch_bounds__(64) void lstm_skew_kernel(
    const float* __restrict__ input,
    const float* __restrict__ w_ih1, const float* __restrict__ w_hh1,
    const float* __restrict__ b_ih1, const float* __restrict__ b_hh1,
    const float* __restrict__ w_ih2, const float* __restrict__ w_hh2,
    const float* __restrict__ b_ih2, const float* __restrict__ b_hh2,
    const float* __restrict__ w_lin, const float* __restrict__ b_lin,
    float* __restrict__ out)
{
  const int lane = threadIdx.x & 63;
  const int g    = lane >> 4;       // unit residue group
  const int n    = lane & 15;       // element column
  const int e0   = blockIdx.x * 16;

  const float L2E = 1.4426950408889634f;
  const float sc[4] = { -L2E, -L2E, 2.0f * L2E, -L2E };  // i,f,g,o prescale
  const float TWO_L2E = 2.885390081777927f;

  // ---------------- A fragments: 3 chunks per cell, prescaled ------------
  v8h A1[3], A2[3];
  {
    const int q = n & 3;
    #pragma unroll
    for (int c = 0; c < 3; ++c) {
      const int v   = 4 * c + (n >> 2);
      const int row = q * 12 + v;
      v8h a1 = {0,0,0,0,0,0,0,0}, a2 = {0,0,0,0,0,0,0,0};
      #pragma unroll
      for (int j = 0; j < 3; ++j) {
        const int u = 4 * j + g;
        a1[j]     = (_Float16)(sc[q] * w_hh1[row * 12 + u]);   // cell1: h1 cols
        a2[j]     = (_Float16)(sc[q] * w_ih2[row * 12 + u]);   // cell2: h1 cols
        a2[j + 4] = (_Float16)(sc[q] * w_hh2[row * 12 + u]);   // cell2: h2 cols
      }
      A1[c] = a1; A2[c] = a2;
    }
  }

  // ---------------- C bias fragments + x weights + y weights -------------
  v4f  C1[3], C2[3];
  float wi1[3][4], wl[3];
  #pragma unroll
  for (int c = 0; c < 3; ++c) {
    const int v = 4 * c + g;
    #pragma unroll
    for (int r = 0; r < 4; ++r) {
      C1[c][r]  = sc[r] * (b_ih1[r * 12 + v] + b_hh1[r * 12 + v]);
      C2[c][r]  = sc[r] * (b_ih2[r * 12 + v] + b_hh2[r * 12 + v]);
      wi1[c][r] = sc[r] * w_ih1[r * 12 + v];
    }
    wl[c] = w_lin[v];
  }
  const float blin = b_lin[0];

  // ---------------- y-partial LDS buffer: [s%16][g][n] f32 = 4 KiB -------
  // write bank = (16g+n)%32 -> 2-way (free). Flush reads 4-way (off-chain).
  __shared__ float yP[16][4][16];

  // ---------------- state (all registers) --------------------------------
  float c1s[3] = {0,0,0}, c2s[3] = {0,0,0};
  float h1f[3] = {0,0,0}, h2f[3] = {0,0,0};   // h1(t-1), h2(t-2) at pack time

  const float* xrow = input + (size_t)(e0 + n) * T;
  float*       yrow = out   + (size_t)(e0 + n) * TT;
  const float  xl   = xrow[T - 1];

  auto act3 = [&](const float (&G)[3][4], float (&cs)[3], float (&h)[3]) {
    float Ai[3], Af[3], Eg[3], Ao[3];
    #pragma unroll
    for (int c = 0; c < 3; ++c) Ai[c] = fexp2(G[c][0]);
    #pragma unroll
    for (int c = 0; c < 3; ++c) Af[c] = fexp2(G[c][1]);
    #pragma unroll
    for (int c = 0; c < 3; ++c) Eg[c] = fexp2(G[c][2]);
    #pragma unroll
    for (int c = 0; c < 3; ++c) Ao[c] = fexp2(G[c][3]);
    float pfx[3], P[3], R[3], Nn[3], Ec[3], R2[3];
    #pragma unroll
    for (int c = 0; c < 3; ++c) { pfx[c] = 1.0f + Af[c]; P[c] = (1.0f + Ai[c]) * (1.0f + Eg[c]); }
    #pragma unroll
    for (int c = 0; c < 3; ++c) R[c]  = frcp(P[c] * pfx[c]);
    #pragma unroll
    for (int c = 0; c < 3; ++c) Nn[c] = fmaf(cs[c], P[c], (Eg[c] - 1.0f) * pfx[c]);
    #pragma unroll
    for (int c = 0; c < 3; ++c) cs[c] = Nn[c] * R[c];
    #pragma unroll
    for (int c = 0; c < 3; ++c) Ec[c] = fexp2(TWO_L2E * cs[c]);
    #pragma unroll
    for (int c = 0; c < 3; ++c) R2[c] = frcp((1.0f + Ao[c]) * (1.0f + Ec[c]));
    #pragma unroll
    for (int c = 0; c < 3; ++c) h[c] = (Ec[c] - 1.0f) * R2[c];
  };

  // Reduce+store one 16-step batch: lane (n, tq=lane>>4) handles 4 t's.
  auto flush = [&](int sbase) {
    const int tq = lane >> 4;
    float ys[4];
    #pragma unroll
    for (int ii = 0; ii < 4; ++ii) {
      const int j = 4 * tq + ii;
      ys[ii] = (yP[j][0][n] + yP[j][1][n]) + (yP[j][2][n] + yP[j][3][n]) + blin;
    }
    *reinterpret_cast<float4*>(yrow + sbase + 4 * tq) =
        make_float4(ys[0], ys[1], ys[2], ys[3]);
  };

  // One substep: cell1(t) and cell2(t-1) from shared B = {h1(t-1), h2(t-2)}.
  auto substep = [&](int t, float x, bool do2) {
    v8h Bv;
    Bv[0] = (_Float16)h1f[0]; Bv[1] = (_Float16)h1f[1]; Bv[2] = (_Float16)h1f[2];
    Bv[3] = (_Float16)0.0f;
    Bv[4] = (_Float16)h2f[0]; Bv[5] = (_Float16)h2f[1]; Bv[6] = (_Float16)h2f[2];
    Bv[7] = (_Float16)0.0f;

    v4f D0 = __builtin_amdgcn_mfma_f32_16x16x32_f16(A1[0], Bv, C1[0], 0, 0, 0);
    v4f D1 = __builtin_amdgcn_mfma_f32_16x16x32_f16(A1[1], Bv, C1[1], 0, 0, 0);
    v4f D2 = __builtin_amdgcn_mfma_f32_16x16x32_f16(A1[2], Bv, C1[2], 0, 0, 0);
    v4f E0 = __builtin_amdgcn_mfma_f32_16x16x32_f16(A2[0], Bv, C2[0], 0, 0, 0);
    v4f E1 = __builtin_amdgcn_mfma_f32_16x16x32_f16(A2[1], Bv, C2[1], 0, 0, 0);
    v4f E2 = __builtin_amdgcn_mfma_f32_16x16x32_f16(A2[2], Bv, C2[2], 0, 0, 0);

    float G1[3][4];
    #pragma unroll
    for (int r = 0; r < 4; ++r) G1[0][r] = fmaf(wi1[0][r], x, D0[r]);
    #pragma unroll
    for (int r = 0; r < 4; ++r) G1[1][r] = fmaf(wi1[1][r], x, D1[r]);
    #pragma unroll
    for (int r = 0; r < 4; ++r) G1[2][r] = fmaf(wi1[2][r], x, D2[r]);
    act3(G1, c1s, h1f);                       // h1f <- h1(t)

    if (do2) {                                // cell2 step s = t-1
      float G2[3][4];
      #pragma unroll
      for (int r = 0; r < 4; ++r) G2[0][r] = E0[r];
      #pragma unroll
      for (int r = 0; r < 4; ++r) G2[1][r] = E1[r];
      #pragma unroll
      for (int r = 0; r < 4; ++r) G2[2][r] = E2[r];
      act3(G2, c2s, h2f);                     // h2f <- h2(t-1)
      float yp = h2f[0] * wl[0];
      yp = fmaf(h2f[1], wl[1], yp);
      yp = fmaf(h2f[2], wl[2], yp);
      yP[(t - 1) & 15][g][n] = yp;            // fire-and-forget
    }
  };

  float4 xv = *reinterpret_cast<const float4*>(xrow);
  for (int t4 = 0; t4 < TT; t4 += 4) {
    float4 xn;
    if (t4 + 4 < T) xn = *reinterpret_cast<const float4*>(xrow + t4 + 4);
    else            xn = make_float4(xl, xl, xl, xl);

    // substep 0: flush previous 16-step batch (slots 0..15 complete after
    // cell2(t4-1) writes slot 15 inside this substep).
    substep(t4 + 0, xv.x, t4 > 0);
    if (t4 > 0 && (t4 & 15) == 0) flush(t4 - 16);
    substep(t4 + 1, xv.y, true);
    substep(t4 + 2, xv.z, true);
    substep(t4 + 3, xv.w, true);
    xv = xn;
  }

  // Epilogue: cell2(TT-1) with h1(TT-1), h2(TT-2); then flush last batch.
  {
    v8h Bv;
    Bv[0] = (_Float16)h1f[0]; Bv[1] = (_Float16)h1f[1]; Bv[2] = (_Float16)h1f[2];
    Bv[3] = (_Float16)0.0f;
    Bv[4] = (_Float16)h2f[0]; Bv[5] = (_Float16)h2f[1]; Bv[6] = (_Float16)h2f[2];
    Bv[7] = (_Float16)0.0f;
    v4f E0 = __builtin_amdgcn_mfma_f32_16x16x32_f16(A2[0], Bv, C2[0], 0, 0, 0);
    v4f E1 = __builtin_amdgcn_mfma_f32_16x16x32_f16(A2[1], Bv, C2[1], 0, 0, 0);
    v4f E2 = __builtin_amdgcn_mfma_f32_16x16x32_f16(A2[2], Bv, C2[2], 0, 0, 0);
    float G2[3][4];
    #pragma unroll
    for (int r = 0; r < 4; ++r) G2[0][r] = E0[r];
    #pragma unroll
    for (int r = 0; r < 4; ++r) G2[1][r] = E1[r];
    #pragma unroll
    for (int r = 0; r < 4; ++r) G2[2][r] = E2[r];
    act3(G2, c2s, h2f);
    float yp = h2f[0] * wl[0];
    yp = fmaf(h2f[1], wl[1], yp);
    yp = fmaf(h2f[2], wl[2], yp);
    yP[15][g][n] = yp;
    flush(TT - 16);
  }
}

extern "C" void kernel_launch(void* const* d_in, const int* in_sizes, int n_in,
                              void* d_out, int out_size, void* d_ws, size_t ws_size,
                              hipStream_t stream) {
  const float* input = (const float*)d_in[0];
  const float* w_ih1 = (const float*)d_in[2];
  const float* w_hh1 = (const float*)d_in[3];
  const float* b_ih1 = (const float*)d_in[4];
  const float* b_hh1 = (const float*)d_in[5];
  const float* w_ih2 = (const float*)d_in[6];
  const float* w_hh2 = (const float*)d_in[7];
  const float* b_ih2 = (const float*)d_in[8];
  const float* b_hh2 = (const float*)d_in[9];
  const float* w_lin = (const float*)d_in[10];
  const float* b_lin = (const float*)d_in[11];
  float* out = (float*)d_out;

  dim3 grid(B / 16);   // 512 single-wave chains; 2 waves per CU
  dim3 block(64);
  hipLaunchKernelGGL(lstm_skew_kernel, grid, block, 0, stream,
                     input, w_ih1, w_hh1, b_ih1, b_hh1,
                     w_ih2, w_hh2, b_ih2, b_hh2, w_lin, b_lin, out);
}

// Round 5
// 565.761 us; speedup vs baseline: 1.1501x; 1.0164x over previous
//
#include <hip/hip_runtime.h>

// 2-layer LSTM (H=12), B=8192, T=1024 + 64 free-running steps.
// R11: CELL-SPLIT WAVE PIPELINE, BARRIER EVERY 4 STEPS.
// R10 post-mortem: single wave/chain is at the per-SIMD ISSUE ceiling
// (~42 wave64 transcendentals/step = 336-672 cy issue; VALUBusy ~78% on the
// 512 active SIMDs; half the chip idle). Trans count is minimal (5 exp +
// 2 rcp per unit-cell, perfectly lane-packed), so the lever is spreading the
// work over 1024 waves: wave0 = cell1 chain, wave1 = cell2 chain + y.
// R9 tried this and failed (1300 cy/step) because it barriered EVERY substep,
// draining the FIFO ds_read prefetch (~120 cy) and ds_write at each barrier.
// R11 barriers once per 4-step iteration with a depth-8 FIFO:
//   iter kb: wave0 writes h1 slots kb..kb+3 (mod 8);
//            wave1 reads slots  kb-4..kb-1 (mod 8)  — disjoint mod 8.
//   RAW (write iter kb -> read iter kb+4... actually next iter) and WAR
//   (read iter kb -> rewrite iter kb+4) pairs are each separated by exactly
//   one end-of-iteration barrier. Wave1 issues all 4 ds_reads at iter top.
// Math/vintages identical to R9/R10 (h1, h2 cross in f16 at the same points).
//
// Layout (harness-verified):
//   Row order R = 4*v + q; chunk c row (lane&15) -> v=4c+(m>>2), q=m&3.
//   K order k = 8*(u%4) + (u/4); B slot (g,j<3) = h_{4j+g} -> lane-local
//   D->B handoff; pads at j=3,7. Cell1 A zeros on h2 slots.
// Fragment maps (gfx950, HW-verified):
//   A[m=lane&15][k=8*(lane>>4)+j], B[k=8*(lane>>4)+j][n=lane&15],
//   D[row=4*(lane>>4)+reg][col=lane&15].

typedef _Float16 v8h  __attribute__((ext_vector_type(8)));
typedef _Float16 v4h  __attribute__((ext_vector_type(4)));
typedef float    v4f  __attribute__((ext_vector_type(4)));

constexpr int T   = 1024;
constexpr int FUT = 64;
constexpr int TT  = T + FUT;   // 1088 (divisible by 4)
constexpr int B   = 8192;

static __device__ __forceinline__ float fexp2(float x){ return __builtin_amdgcn_exp2f(x); }
static __device__ __forceinline__ float frcp (float x){ return __builtin_amdgcn_rcpf(x); }

__global__ __launch_bounds__(128) void lstm_pipe4_kernel(
    const float* __restrict__ input,
    const float* __restrict__ w_ih1, const float* __restrict__ w_hh1,
    const float* __restrict__ b_ih1, const float* __restrict__ b_hh1,
    const float* __restrict__ w_ih2, const float* __restrict__ w_hh2,
    const float* __restrict__ b_ih2, const float* __restrict__ b_hh2,
    const float* __restrict__ w_lin, const float* __restrict__ b_lin,
    float* __restrict__ out)
{
  const int tid  = threadIdx.x;
  const int wid  = tid >> 6;        // 0 = cell1 producer, 1 = cell2 consumer
  const int lane = tid & 63;
  const int g    = lane >> 4;       // unit residue group
  const int n    = lane & 15;       // element column
  const int e0   = blockIdx.x * 16;

  const float L2E = 1.4426950408889634f;
  const float sc[4] = { -L2E, -L2E, 2.0f * L2E, -L2E };  // i,f,g,o prescale
  const float TWO_L2E = 2.885390081777927f;

  // ---- per-wave fragment set: wave0 = cell1, wave1 = cell2 ---------------
  v8h Aw[3]; v4f Cw[3];
  float wix[3][4];   // wave0: prescaled w_ih1; wave1: unused (0)
  float wl[3] = {0,0,0};
  {
    const int q = n & 3;
    #pragma unroll
    for (int c = 0; c < 3; ++c) {
      const int v   = 4 * c + (n >> 2);
      const int row = q * 12 + v;
      v8h a = {0,0,0,0,0,0,0,0};
      if (wid == 0) {
        #pragma unroll
        for (int j = 0; j < 3; ++j)
          a[j] = (_Float16)(sc[q] * w_hh1[row * 12 + (4 * j + g)]);
      } else {
        #pragma unroll
        for (int j = 0; j < 3; ++j) {
          const int u = 4 * j + g;
          a[j]     = (_Float16)(sc[q] * w_ih2[row * 12 + u]);  // h1 cols
          a[j + 4] = (_Float16)(sc[q] * w_hh2[row * 12 + u]);  // h2 cols
        }
      }
      Aw[c] = a;
    }
    #pragma unroll
    for (int c = 0; c < 3; ++c) {
      const int v = 4 * c + g;
      #pragma unroll
      for (int r = 0; r < 4; ++r) {
        if (wid == 0) {
          Cw[c][r]  = sc[r] * (b_ih1[r * 12 + v] + b_hh1[r * 12 + v]);
          wix[c][r] = sc[r] * w_ih1[r * 12 + v];
        } else {
          Cw[c][r]  = sc[r] * (b_ih2[r * 12 + v] + b_hh2[r * 12 + v]);
          wix[c][r] = 0.0f;
        }
      }
      if (wid == 1) wl[c] = w_lin[v];
    }
  }
  const float blin = b_lin[0];

  // ---- LDS FIFO: 8 slots x 64 lanes x 8 B = 4 KiB ------------------------
  __shared__ v4h fifo[8][64];

  // ---- per-wave recurrent state (registers) ------------------------------
  float csw[3] = {0,0,0};
  v8h  Bw = {0,0,0,0,0,0,0,0};

  const float* xrow = input + (size_t)(e0 + n) * T;
  float*       yrow = out   + (size_t)(e0 + n) * TT;
  const float  xl   = xrow[T - 1];

  auto act3 = [&](const float (&G)[3][4], float (&h)[3]) {
    float Ai[3], Af[3], Eg[3], Ao[3];
    #pragma unroll
    for (int c = 0; c < 3; ++c) Ai[c] = fexp2(G[c][0]);
    #pragma unroll
    for (int c = 0; c < 3; ++c) Af[c] = fexp2(G[c][1]);
    #pragma unroll
    for (int c = 0; c < 3; ++c) Eg[c] = fexp2(G[c][2]);
    #pragma unroll
    for (int c = 0; c < 3; ++c) Ao[c] = fexp2(G[c][3]);
    float pfx[3], P[3], R[3], Nn[3], Ec[3], R2[3];
    #pragma unroll
    for (int c = 0; c < 3; ++c) { pfx[c] = 1.0f + Af[c]; P[c] = (1.0f + Ai[c]) * (1.0f + Eg[c]); }
    #pragma unroll
    for (int c = 0; c < 3; ++c) R[c]  = frcp(P[c] * pfx[c]);
    #pragma unroll
    for (int c = 0; c < 3; ++c) Nn[c] = fmaf(csw[c], P[c], (Eg[c] - 1.0f) * pfx[c]);
    #pragma unroll
    for (int c = 0; c < 3; ++c) csw[c] = Nn[c] * R[c];
    #pragma unroll
    for (int c = 0; c < 3; ++c) Ec[c] = fexp2(TWO_L2E * csw[c]);
    #pragma unroll
    for (int c = 0; c < 3; ++c) R2[c] = frcp((1.0f + Ao[c]) * (1.0f + Ec[c]));
    #pragma unroll
    for (int c = 0; c < 3; ++c) h[c] = (Ec[c] - 1.0f) * R2[c];
  };

  // wave0: one cell1 step at time t; push h1(t) into FIFO slot t%8
  auto stepA = [&](int t, float x) {
    v4f D0 = __builtin_amdgcn_mfma_f32_16x16x32_f16(Aw[0], Bw, Cw[0], 0, 0, 0);
    v4f D1 = __builtin_amdgcn_mfma_f32_16x16x32_f16(Aw[1], Bw, Cw[1], 0, 0, 0);
    v4f D2 = __builtin_amdgcn_mfma_f32_16x16x32_f16(Aw[2], Bw, Cw[2], 0, 0, 0);
    float G[3][4], h[3];
    #pragma unroll
    for (int r = 0; r < 4; ++r) G[0][r] = fmaf(wix[0][r], x, D0[r]);
    #pragma unroll
    for (int r = 0; r < 4; ++r) G[1][r] = fmaf(wix[1][r], x, D1[r]);
    #pragma unroll
    for (int r = 0; r < 4; ++r) G[2][r] = fmaf(wix[2][r], x, D2[r]);
    act3(G, h);
    v4h pk;
    pk[0] = (_Float16)h[0]; pk[1] = (_Float16)h[1];
    pk[2] = (_Float16)h[2]; pk[3] = (_Float16)0.0f;
    fifo[t & 7][lane] = pk;
    Bw[0] = pk[0]; Bw[1] = pk[1]; Bw[2] = pk[2];
  };

  // wave1: one cell2 step at time t with prefetched h1(t); produce y(t)
  auto stepB = [&](v4h pf, float& ybs) {
    Bw[0] = pf[0]; Bw[1] = pf[1]; Bw[2] = pf[2];
    v4f E0 = __builtin_amdgcn_mfma_f32_16x16x32_f16(Aw[0], Bw, Cw[0], 0, 0, 0);
    v4f E1 = __builtin_amdgcn_mfma_f32_16x16x32_f16(Aw[1], Bw, Cw[1], 0, 0, 0);
    v4f E2 = __builtin_amdgcn_mfma_f32_16x16x32_f16(Aw[2], Bw, Cw[2], 0, 0, 0);
    float G[3][4], h[3];
    #pragma unroll
    for (int r = 0; r < 4; ++r) G[0][r] = E0[r];
    #pragma unroll
    for (int r = 0; r < 4; ++r) G[1][r] = E1[r];
    #pragma unroll
    for (int r = 0; r < 4; ++r) G[2][r] = E2[r];
    act3(G, h);
    Bw[4] = (_Float16)h[0]; Bw[5] = (_Float16)h[1]; Bw[6] = (_Float16)h[2];
    float yp = h[0] * wl[0];
    yp = fmaf(h[1], wl[1], yp);
    yp = fmaf(h[2], wl[2], yp);
    yp += __shfl_xor(yp, 16);
    yp += __shfl_xor(yp, 32);
    ybs = yp + blin;
  };

  float4 xv = make_float4(0.f, 0.f, 0.f, 0.f);
  if (wid == 0) xv = *reinterpret_cast<const float4*>(xrow);

  for (int kb = 0; kb <= TT; kb += 4) {
    if (wid == 0) {
      if (kb < TT) {
        float4 xn;
        if (kb + 4 < T) xn = *reinterpret_cast<const float4*>(xrow + kb + 4);
        else            xn = make_float4(xl, xl, xl, xl);
        stepA(kb + 0, xv.x);
        stepA(kb + 1, xv.y);
        stepA(kb + 2, xv.z);
        stepA(kb + 3, xv.w);
        xv = xn;
      }
    } else {
      if (kb >= 4) {
        const int s = kb - 4;
        // all 4 slots were written last iteration (one barrier ago)
        v4h p0 = fifo[(s + 0) & 7][lane];
        v4h p1 = fifo[(s + 1) & 7][lane];
        v4h p2 = fifo[(s + 2) & 7][lane];
        v4h p3 = fifo[(s + 3) & 7][lane];
        float4 yb;
        stepB(p0, yb.x);
        stepB(p1, yb.y);
        stepB(p2, yb.z);
        stepB(p3, yb.w);
        if (g == 3) *reinterpret_cast<float4*>(yrow + s) = yb;
      }
    }
    __syncthreads();
  }
}

extern "C" void kernel_launch(void* const* d_in, const int* in_sizes, int n_in,
                              void* d_out, int out_size, void* d_ws, size_t ws_size,
                              hipStream_t stream) {
  const float* input = (const float*)d_in[0];
  const float* w_ih1 = (const float*)d_in[2];
  const float* w_hh1 = (const float*)d_in[3];
  const float* b_ih1 = (const float*)d_in[4];
  const float* b_hh1 = (const float*)d_in[5];
  const float* w_ih2 = (const float*)d_in[6];
  const float* w_hh2 = (const float*)d_in[7];
  const float* b_ih2 = (const float*)d_in[8];
  const float* b_hh2 = (const float*)d_in[9];
  const float* w_lin = (const float*)d_in[10];
  const float* b_lin = (const float*)d_in[11];
  float* out = (float*)d_out;

  dim3 grid(B / 16);   // 512 blocks x 2 waves = 1024 waves = 1 per SIMD
  dim3 block(128);
  hipLaunchKernelGGL(lstm_pipe4_kernel, grid, block, 0, stream,
                     input, w_ih1, w_hh1, b_ih1, b_hh1,
                     w_ih2, w_hh2, b_ih2, b_hh2, w_lin, b_lin, out);
}

// Round 6
// 553.540 us; speedup vs baseline: 1.1755x; 1.0221x over previous
//
#include <hip/hip_runtime.h>

// 2-layer LSTM (H=12), B=8192, T=1024 + 64 free-running steps.
// R12: CELL-SPLIT PIPELINE (R11) + STRIPPED CONSUMER BODY.
// R11 post-mortem: halving per-wave work changed nothing (507 vs 512 us).
// Hypotheses: (a) both waves co-scheduled on one SIMD (issue re-serialized),
// (b) wave1's body was NOT light: __shfl_xor x2/step = ds_bpermute +
//     lgkmcnt waits (~60 cy each, unhidable on an in-order lone wave),
//     plus G-copies and MFMA hazards, plus barrier-lockstep skew.
// R12 attacks (b): wave1's y-reduction leaves the loop — per-lane y-partials
// go to an LDS buffer via fire-and-forget ds_write (bank-free), reduced and
// float4-stored once per 16 steps (R10's proven pattern). No shuffle, no
// lgkm wait on the recurrence. Barrier stays at 4-step cadence (depth-8 FIFO,
// RAW/WAR pairs separated by exactly one barrier, disjoint slot sets mod 8).
// Math/vintages identical to R9-R11 (absmax must stay 2.441e-4).
//
// Layout (harness-verified):
//   Row order R = 4*v + q; chunk c row (lane&15) -> v=4c+(m>>2), q=m&3.
//   K order k = 8*(u%4) + (u/4); B slot (g,j<3) = h_{4j+g} -> lane-local
//   D->B handoff; pads at j=3,7. Cell1 A zeros on h2 slots.
// Fragment maps (gfx950, HW-verified):
//   A[m=lane&15][k=8*(lane>>4)+j], B[k=8*(lane>>4)+j][n=lane&15],
//   D[row=4*(lane>>4)+reg][col=lane&15].

typedef _Float16 v8h  __attribute__((ext_vector_type(8)));
typedef _Float16 v4h  __attribute__((ext_vector_type(4)));
typedef float    v4f  __attribute__((ext_vector_type(4)));

constexpr int T   = 1024;
constexpr int FUT = 64;
constexpr int TT  = T + FUT;   // 1088 = 68*16 (flush-aligned)
constexpr int B   = 8192;

static __device__ __forceinline__ float fexp2(float x){ return __builtin_amdgcn_exp2f(x); }
static __device__ __forceinline__ float frcp (float x){ return __builtin_amdgcn_rcpf(x); }

__global__ __launch_bounds__(128) void lstm_split_kernel(
    const float* __restrict__ input,
    const float* __restrict__ w_ih1, const float* __restrict__ w_hh1,
    const float* __restrict__ b_ih1, const float* __restrict__ b_hh1,
    const float* __restrict__ w_ih2, const float* __restrict__ w_hh2,
    const float* __restrict__ b_ih2, const float* __restrict__ b_hh2,
    const float* __restrict__ w_lin, const float* __restrict__ b_lin,
    float* __restrict__ out)
{
  const int tid  = threadIdx.x;
  const int wid  = tid >> 6;        // 0 = cell1 producer, 1 = cell2 consumer
  const int lane = tid & 63;
  const int g    = lane >> 4;       // unit residue group
  const int n    = lane & 15;       // element column
  const int e0   = blockIdx.x * 16;

  const float L2E = 1.4426950408889634f;
  const float sc[4] = { -L2E, -L2E, 2.0f * L2E, -L2E };  // i,f,g,o prescale
  const float TWO_L2E = 2.885390081777927f;

  // ---- per-wave fragment set: wave0 = cell1, wave1 = cell2 ---------------
  v8h Aw[3]; v4f Cw[3];
  float wix[3][4];   // wave0 only: prescaled w_ih1
  float wl[3] = {0,0,0};
  {
    const int q = n & 3;
    #pragma unroll
    for (int c = 0; c < 3; ++c) {
      const int v   = 4 * c + (n >> 2);
      const int row = q * 12 + v;
      v8h a = {0,0,0,0,0,0,0,0};
      if (wid == 0) {
        #pragma unroll
        for (int j = 0; j < 3; ++j)
          a[j] = (_Float16)(sc[q] * w_hh1[row * 12 + (4 * j + g)]);
      } else {
        #pragma unroll
        for (int j = 0; j < 3; ++j) {
          const int u = 4 * j + g;
          a[j]     = (_Float16)(sc[q] * w_ih2[row * 12 + u]);  // h1 cols
          a[j + 4] = (_Float16)(sc[q] * w_hh2[row * 12 + u]);  // h2 cols
        }
      }
      Aw[c] = a;
    }
    #pragma unroll
    for (int c = 0; c < 3; ++c) {
      const int v = 4 * c + g;
      #pragma unroll
      for (int r = 0; r < 4; ++r) {
        if (wid == 0) {
          Cw[c][r]  = sc[r] * (b_ih1[r * 12 + v] + b_hh1[r * 12 + v]);
          wix[c][r] = sc[r] * w_ih1[r * 12 + v];
        } else {
          Cw[c][r]  = sc[r] * (b_ih2[r * 12 + v] + b_hh2[r * 12 + v]);
          wix[c][r] = 0.0f;
        }
      }
      if (wid == 1) wl[c] = w_lin[v];
    }
  }
  const float blin = b_lin[0];

  // ---- LDS: h1 FIFO (4 KiB) + y-partial buffer (4 KiB) -------------------
  __shared__ v4h  fifo[8][64];
  __shared__ float yP[16][4][16];   // [s%16][g][n]; write bank 2-way = free

  // ---- per-wave recurrent state (registers) ------------------------------
  float csw[3] = {0,0,0};
  v8h  Bw = {0,0,0,0,0,0,0,0};

  const float* xrow = input + (size_t)(e0 + n) * T;
  float*       yrow = out   + (size_t)(e0 + n) * TT;
  const float  xl   = xrow[T - 1];

  auto act3 = [&](const float (&G)[3][4], float (&h)[3]) {
    float Ai[3], Af[3], Eg[3], Ao[3];
    #pragma unroll
    for (int c = 0; c < 3; ++c) Ai[c] = fexp2(G[c][0]);
    #pragma unroll
    for (int c = 0; c < 3; ++c) Af[c] = fexp2(G[c][1]);
    #pragma unroll
    for (int c = 0; c < 3; ++c) Eg[c] = fexp2(G[c][2]);
    #pragma unroll
    for (int c = 0; c < 3; ++c) Ao[c] = fexp2(G[c][3]);
    float pfx[3], P[3], R[3], Nn[3], Ec[3], R2[3];
    #pragma unroll
    for (int c = 0; c < 3; ++c) { pfx[c] = 1.0f + Af[c]; P[c] = (1.0f + Ai[c]) * (1.0f + Eg[c]); }
    #pragma unroll
    for (int c = 0; c < 3; ++c) R[c]  = frcp(P[c] * pfx[c]);
    #pragma unroll
    for (int c = 0; c < 3; ++c) Nn[c] = fmaf(csw[c], P[c], (Eg[c] - 1.0f) * pfx[c]);
    #pragma unroll
    for (int c = 0; c < 3; ++c) csw[c] = Nn[c] * R[c];
    #pragma unroll
    for (int c = 0; c < 3; ++c) Ec[c] = fexp2(TWO_L2E * csw[c]);
    #pragma unroll
    for (int c = 0; c < 3; ++c) R2[c] = frcp((1.0f + Ao[c]) * (1.0f + Ec[c]));
    #pragma unroll
    for (int c = 0; c < 3; ++c) h[c] = (Ec[c] - 1.0f) * R2[c];
  };

  // wave0: one cell1 step at time t; push h1(t) into FIFO slot t%8
  auto stepA = [&](int t, float x) {
    v4f D0 = __builtin_amdgcn_mfma_f32_16x16x32_f16(Aw[0], Bw, Cw[0], 0, 0, 0);
    v4f D1 = __builtin_amdgcn_mfma_f32_16x16x32_f16(Aw[1], Bw, Cw[1], 0, 0, 0);
    v4f D2 = __builtin_amdgcn_mfma_f32_16x16x32_f16(Aw[2], Bw, Cw[2], 0, 0, 0);
    float G[3][4], h[3];
    #pragma unroll
    for (int r = 0; r < 4; ++r) G[0][r] = fmaf(wix[0][r], x, D0[r]);
    #pragma unroll
    for (int r = 0; r < 4; ++r) G[1][r] = fmaf(wix[1][r], x, D1[r]);
    #pragma unroll
    for (int r = 0; r < 4; ++r) G[2][r] = fmaf(wix[2][r], x, D2[r]);
    act3(G, h);
    v4h pk;
    pk[0] = (_Float16)h[0]; pk[1] = (_Float16)h[1];
    pk[2] = (_Float16)h[2]; pk[3] = (_Float16)0.0f;
    fifo[t & 7][lane] = pk;                      // fire-and-forget
    Bw[0] = pk[0]; Bw[1] = pk[1]; Bw[2] = pk[2];
  };

  // wave1: one cell2 step s with prefetched h1(s); y-partial -> LDS
  auto stepB = [&](v4h pf, int s) {
    Bw[0] = pf[0]; Bw[1] = pf[1]; Bw[2] = pf[2];
    v4f E0 = __builtin_amdgcn_mfma_f32_16x16x32_f16(Aw[0], Bw, Cw[0], 0, 0, 0);
    v4f E1 = __builtin_amdgcn_mfma_f32_16x16x32_f16(Aw[1], Bw, Cw[1], 0, 0, 0);
    v4f E2 = __builtin_amdgcn_mfma_f32_16x16x32_f16(Aw[2], Bw, Cw[2], 0, 0, 0);
    float G[3][4], h[3];
    #pragma unroll
    for (int r = 0; r < 4; ++r) G[0][r] = E0[r];
    #pragma unroll
    for (int r = 0; r < 4; ++r) G[1][r] = E1[r];
    #pragma unroll
    for (int r = 0; r < 4; ++r) G[2][r] = E2[r];
    act3(G, h);
    Bw[4] = (_Float16)h[0]; Bw[5] = (_Float16)h[1]; Bw[6] = (_Float16)h[2];
    float yp = h[0] * wl[0];
    yp = fmaf(h[1], wl[1], yp);
    yp = fmaf(h[2], wl[2], yp);
    yP[s & 15][g][n] = yp;                       // fire-and-forget
  };

  // wave1: reduce + store one 16-step batch (own writes; no cross-wave dep)
  auto flush = [&](int sbase) {
    const int tq = lane >> 4;
    float ys[4];
    #pragma unroll
    for (int ii = 0; ii < 4; ++ii) {
      const int j = 4 * tq + ii;
      ys[ii] = (yP[j][0][n] + yP[j][1][n]) + (yP[j][2][n] + yP[j][3][n]) + blin;
    }
    *reinterpret_cast<float4*>(yrow + sbase + 4 * tq) =
        make_float4(ys[0], ys[1], ys[2], ys[3]);
  };

  float4 xv = make_float4(0.f, 0.f, 0.f, 0.f);
  if (wid == 0) xv = *reinterpret_cast<const float4*>(xrow);

  for (int kb = 0; kb <= TT; kb += 4) {
    if (wid == 0) {
      if (kb < TT) {
        float4 xn;
        if (kb + 4 < T) xn = *reinterpret_cast<const float4*>(xrow + kb + 4);
        else            xn = make_float4(xl, xl, xl, xl);
        stepA(kb + 0, xv.x);
        stepA(kb + 1, xv.y);
        stepA(kb + 2, xv.z);
        stepA(kb + 3, xv.w);
        xv = xn;
      }
    } else {
      if (kb >= 4) {
        const int s = kb - 4;
        // all 4 slots written last iteration (one barrier ago); disjoint mod 8
        v4h p0 = fifo[(s + 0) & 7][lane];
        v4h p1 = fifo[(s + 1) & 7][lane];
        v4h p2 = fifo[(s + 2) & 7][lane];
        v4h p3 = fifo[(s + 3) & 7][lane];
        stepB(p0, s + 0);
        stepB(p1, s + 1);
        stepB(p2, s + 2);
        stepB(p3, s + 3);
        if ((kb & 15) == 0 && kb >= 16) flush(kb - 16);
      }
    }
    __syncthreads();
  }
}

extern "C" void kernel_launch(void* const* d_in, const int* in_sizes, int n_in,
                              void* d_out, int out_size, void* d_ws, size_t ws_size,
                              hipStream_t stream) {
  const float* input = (const float*)d_in[0];
  const float* w_ih1 = (const float*)d_in[2];
  const float* w_hh1 = (const float*)d_in[3];
  const float* b_ih1 = (const float*)d_in[4];
  const float* b_hh1 = (const float*)d_in[5];
  const float* w_ih2 = (const float*)d_in[6];
  const float* w_hh2 = (const float*)d_in[7];
  const float* b_ih2 = (const float*)d_in[8];
  const float* b_hh2 = (const float*)d_in[9];
  const float* w_lin = (const float*)d_in[10];
  const float* b_lin = (const float*)d_in[11];
  float* out = (float*)d_out;

  dim3 grid(B / 16);   // 512 blocks x 2 waves = 1024 waves
  dim3 block(128);
  hipLaunchKernelGGL(lstm_split_kernel, grid, block, 0, stream,
                     input, w_ih1, w_hh1, b_ih1, b_hh1,
                     w_ih2, w_hh2, b_ih2, b_hh2, w_lin, b_lin, out);
}

// Round 7
// 543.974 us; speedup vs baseline: 1.1961x; 1.0176x over previous
//
#include <hip/hip_runtime.h>

// 2-layer LSTM (H=12), B=8192, T=1024 + 64 free-running steps.
// R13: CELL-SPLIT PIPELINE, 8-STEP BARRIER CADENCE, PRE-HIDDEN LATENCY.
// R12 counters: per-wave issue 430 cy/step (matches static count; trans~16cy
// wave64), but 640 cy/step stall. Prime suspect: __syncthreads every 4 steps
// drains vmcnt(0)/lgkmcnt(0); wave0's x-load was issued late in the body so
// the drain exposed L2/HBM latency every iteration; plus 4-step rendezvous
// skew. R13: barrier every 8 steps (depth-16 FIFO), x-loads for the NEXT
// iteration issued at body TOP (~3500 cy before the drain -> drain free),
// wave1's 8 fifo ds_reads issued at body top. Math identical to R10-R12
// (absmax canary: must stay exactly 2.441e-4).
// FIFO safety: iter kb: w0 writes slots kb..kb+7 (mod 16), w1 reads
// kb-8..kb-1 (mod 16) — disjoint halves; every RAW/WAR pair is separated by
// exactly one end-of-iteration barrier.
//
// Layout (harness-verified):
//   Row order R = 4*v + q; chunk c row (lane&15) -> v=4c+(m>>2), q=m&3.
//   K order k = 8*(u%4) + (u/4); B slot (g,j<3) = h_{4j+g} -> lane-local
//   D->B handoff; pads at j=3,7. Cell1 A zeros on h2 slots.
// Fragment maps (gfx950, HW-verified):
//   A[m=lane&15][k=8*(lane>>4)+j], B[k=8*(lane>>4)+j][n=lane&15],
//   D[row=4*(lane>>4)+reg][col=lane&15].

typedef _Float16 v8h  __attribute__((ext_vector_type(8)));
typedef _Float16 v4h  __attribute__((ext_vector_type(4)));
typedef float    v4f  __attribute__((ext_vector_type(4)));

constexpr int T   = 1024;
constexpr int FUT = 64;
constexpr int TT  = T + FUT;   // 1088 = 68*16 (flush-aligned, 8 | T)
constexpr int B   = 8192;

static __device__ __forceinline__ float fexp2(float x){ return __builtin_amdgcn_exp2f(x); }
static __device__ __forceinline__ float frcp (float x){ return __builtin_amdgcn_rcpf(x); }

__global__ __launch_bounds__(128) void lstm_split8_kernel(
    const float* __restrict__ input,
    const float* __restrict__ w_ih1, const float* __restrict__ w_hh1,
    const float* __restrict__ b_ih1, const float* __restrict__ b_hh1,
    const float* __restrict__ w_ih2, const float* __restrict__ w_hh2,
    const float* __restrict__ b_ih2, const float* __restrict__ b_hh2,
    const float* __restrict__ w_lin, const float* __restrict__ b_lin,
    float* __restrict__ out)
{
  const int tid  = threadIdx.x;
  const int wid  = tid >> 6;        // 0 = cell1 producer, 1 = cell2 consumer
  const int lane = tid & 63;
  const int g    = lane >> 4;       // unit residue group
  const int n    = lane & 15;       // element column
  const int e0   = blockIdx.x * 16;

  const float L2E = 1.4426950408889634f;
  const float sc[4] = { -L2E, -L2E, 2.0f * L2E, -L2E };  // i,f,g,o prescale
  const float TWO_L2E = 2.885390081777927f;

  // ---- per-wave fragment set: wave0 = cell1, wave1 = cell2 ---------------
  v8h Aw[3]; v4f Cw[3];
  float wix[3][4];   // wave0 only: prescaled w_ih1
  float wl[3] = {0,0,0};
  {
    const int q = n & 3;
    #pragma unroll
    for (int c = 0; c < 3; ++c) {
      const int v   = 4 * c + (n >> 2);
      const int row = q * 12 + v;
      v8h a = {0,0,0,0,0,0,0,0};
      if (wid == 0) {
        #pragma unroll
        for (int j = 0; j < 3; ++j)
          a[j] = (_Float16)(sc[q] * w_hh1[row * 12 + (4 * j + g)]);
      } else {
        #pragma unroll
        for (int j = 0; j < 3; ++j) {
          const int u = 4 * j + g;
          a[j]     = (_Float16)(sc[q] * w_ih2[row * 12 + u]);  // h1 cols
          a[j + 4] = (_Float16)(sc[q] * w_hh2[row * 12 + u]);  // h2 cols
        }
      }
      Aw[c] = a;
    }
    #pragma unroll
    for (int c = 0; c < 3; ++c) {
      const int v = 4 * c + g;
      #pragma unroll
      for (int r = 0; r < 4; ++r) {
        if (wid == 0) {
          Cw[c][r]  = sc[r] * (b_ih1[r * 12 + v] + b_hh1[r * 12 + v]);
          wix[c][r] = sc[r] * w_ih1[r * 12 + v];
        } else {
          Cw[c][r]  = sc[r] * (b_ih2[r * 12 + v] + b_hh2[r * 12 + v]);
          wix[c][r] = 0.0f;
        }
      }
      if (wid == 1) wl[c] = w_lin[v];
    }
  }
  const float blin = b_lin[0];

  // ---- LDS: h1 FIFO depth 16 (8 KiB) + y-partial buffer (4 KiB) ----------
  __shared__ v4h  fifo[16][64];
  __shared__ float yP[16][4][16];   // [s%16][g][n]; write bank 2-way = free

  // ---- per-wave recurrent state (registers) ------------------------------
  float csw[3] = {0,0,0};
  v8h  Bw = {0,0,0,0,0,0,0,0};

  const float* xrow = input + (size_t)(e0 + n) * T;
  float*       yrow = out   + (size_t)(e0 + n) * TT;
  const float  xl   = xrow[T - 1];

  auto act3 = [&](const float (&G)[3][4], float (&h)[3]) {
    float Ai[3], Af[3], Eg[3], Ao[3];
    #pragma unroll
    for (int c = 0; c < 3; ++c) Ai[c] = fexp2(G[c][0]);
    #pragma unroll
    for (int c = 0; c < 3; ++c) Af[c] = fexp2(G[c][1]);
    #pragma unroll
    for (int c = 0; c < 3; ++c) Eg[c] = fexp2(G[c][2]);
    #pragma unroll
    for (int c = 0; c < 3; ++c) Ao[c] = fexp2(G[c][3]);
    float pfx[3], P[3], R[3], Nn[3], Ec[3], R2[3];
    #pragma unroll
    for (int c = 0; c < 3; ++c) { pfx[c] = 1.0f + Af[c]; P[c] = (1.0f + Ai[c]) * (1.0f + Eg[c]); }
    #pragma unroll
    for (int c = 0; c < 3; ++c) R[c]  = frcp(P[c] * pfx[c]);
    #pragma unroll
    for (int c = 0; c < 3; ++c) Nn[c] = fmaf(csw[c], P[c], (Eg[c] - 1.0f) * pfx[c]);
    #pragma unroll
    for (int c = 0; c < 3; ++c) csw[c] = Nn[c] * R[c];
    #pragma unroll
    for (int c = 0; c < 3; ++c) Ec[c] = fexp2(TWO_L2E * csw[c]);
    #pragma unroll
    for (int c = 0; c < 3; ++c) R2[c] = frcp((1.0f + Ao[c]) * (1.0f + Ec[c]));
    #pragma unroll
    for (int c = 0; c < 3; ++c) h[c] = (Ec[c] - 1.0f) * R2[c];
  };

  // wave0: one cell1 step at time t; push h1(t) into FIFO slot t%16
  auto stepA = [&](int t, float x) {
    v4f D0 = __builtin_amdgcn_mfma_f32_16x16x32_f16(Aw[0], Bw, Cw[0], 0, 0, 0);
    v4f D1 = __builtin_amdgcn_mfma_f32_16x16x32_f16(Aw[1], Bw, Cw[1], 0, 0, 0);
    v4f D2 = __builtin_amdgcn_mfma_f32_16x16x32_f16(Aw[2], Bw, Cw[2], 0, 0, 0);
    float G[3][4], h[3];
    #pragma unroll
    for (int r = 0; r < 4; ++r) G[0][r] = fmaf(wix[0][r], x, D0[r]);
    #pragma unroll
    for (int r = 0; r < 4; ++r) G[1][r] = fmaf(wix[1][r], x, D1[r]);
    #pragma unroll
    for (int r = 0; r < 4; ++r) G[2][r] = fmaf(wix[2][r], x, D2[r]);
    act3(G, h);
    v4h pk;
    pk[0] = (_Float16)h[0]; pk[1] = (_Float16)h[1];
    pk[2] = (_Float16)h[2]; pk[3] = (_Float16)0.0f;
    fifo[t & 15][lane] = pk;                     // fire-and-forget
    Bw[0] = pk[0]; Bw[1] = pk[1]; Bw[2] = pk[2];
  };

  // wave1: one cell2 step s with prefetched h1(s); y-partial -> LDS
  auto stepB = [&](v4h pf, int s) {
    Bw[0] = pf[0]; Bw[1] = pf[1]; Bw[2] = pf[2];
    v4f E0 = __builtin_amdgcn_mfma_f32_16x16x32_f16(Aw[0], Bw, Cw[0], 0, 0, 0);
    v4f E1 = __builtin_amdgcn_mfma_f32_16x16x32_f16(Aw[1], Bw, Cw[1], 0, 0, 0);
    v4f E2 = __builtin_amdgcn_mfma_f32_16x16x32_f16(Aw[2], Bw, Cw[2], 0, 0, 0);
    float G[3][4], h[3];
    #pragma unroll
    for (int r = 0; r < 4; ++r) G[0][r] = E0[r];
    #pragma unroll
    for (int r = 0; r < 4; ++r) G[1][r] = E1[r];
    #pragma unroll
    for (int r = 0; r < 4; ++r) G[2][r] = E2[r];
    act3(G, h);
    Bw[4] = (_Float16)h[0]; Bw[5] = (_Float16)h[1]; Bw[6] = (_Float16)h[2];
    float yp = h[0] * wl[0];
    yp = fmaf(h[1], wl[1], yp);
    yp = fmaf(h[2], wl[2], yp);
    yP[s & 15][g][n] = yp;                       // fire-and-forget
  };

  // wave1: reduce + store one 16-step batch (own writes; same-wave ordering)
  auto flush = [&](int sbase) {
    const int tq = lane >> 4;
    float ys[4];
    #pragma unroll
    for (int ii = 0; ii < 4; ++ii) {
      const int j = 4 * tq + ii;
      ys[ii] = (yP[j][0][n] + yP[j][1][n]) + (yP[j][2][n] + yP[j][3][n]) + blin;
    }
    *reinterpret_cast<float4*>(yrow + sbase + 4 * tq) =
        make_float4(ys[0], ys[1], ys[2], ys[3]);
  };

  // Prologue x: steps 0..7 (direct load; waits once before the loop).
  float4 xc0 = make_float4(0,0,0,0), xc1 = xc0;
  if (wid == 0) {
    xc0 = *reinterpret_cast<const float4*>(xrow);
    xc1 = *reinterpret_cast<const float4*>(xrow + 4);
  }

  for (int kb = 0; kb <= TT; kb += 8) {
    if (wid == 0) {
      if (kb < TT) {
        // Issue NEXT iteration's x-loads FIRST: ~3500 cy before the barrier
        // drain, so vmcnt(0) at __syncthreads is free.
        float4 xn0, xn1;
        const int nb = kb + 8;
        if (nb < T) {
          xn0 = *reinterpret_cast<const float4*>(xrow + nb);
          xn1 = *reinterpret_cast<const float4*>(xrow + nb + 4);
        } else {
          xn0 = make_float4(xl, xl, xl, xl);
          xn1 = xn0;
        }
        stepA(kb + 0, xc0.x);
        stepA(kb + 1, xc0.y);
        stepA(kb + 2, xc0.z);
        stepA(kb + 3, xc0.w);
        stepA(kb + 4, xc1.x);
        stepA(kb + 5, xc1.y);
        stepA(kb + 6, xc1.z);
        stepA(kb + 7, xc1.w);
        xc0 = xn0; xc1 = xn1;
      }
    } else {
      if (kb >= 8) {
        const int s0 = kb - 8;
        // all 8 slots written last iteration (one barrier ago); issue all
        // ds_reads up front so only the first use waits.
        v4h p0 = fifo[(s0 + 0) & 15][lane];
        v4h p1 = fifo[(s0 + 1) & 15][lane];
        v4h p2 = fifo[(s0 + 2) & 15][lane];
        v4h p3 = fifo[(s0 + 3) & 15][lane];
        v4h p4 = fifo[(s0 + 4) & 15][lane];
        v4h p5 = fifo[(s0 + 5) & 15][lane];
        v4h p6 = fifo[(s0 + 6) & 15][lane];
        v4h p7 = fifo[(s0 + 7) & 15][lane];
        stepB(p0, s0 + 0);
        stepB(p1, s0 + 1);
        stepB(p2, s0 + 2);
        stepB(p3, s0 + 3);
        stepB(p4, s0 + 4);
        stepB(p5, s0 + 5);
        stepB(p6, s0 + 6);
        stepB(p7, s0 + 7);
        if ((kb & 15) == 0) flush(kb - 16);   // steps kb-16..kb-1 all done
      }
    }
    __syncthreads();
  }
}

extern "C" void kernel_launch(void* const* d_in, const int* in_sizes, int n_in,
                              void* d_out, int out_size, void* d_ws, size_t ws_size,
                              hipStream_t stream) {
  const float* input = (const float*)d_in[0];
  const float* w_ih1 = (const float*)d_in[2];
  const float* w_hh1 = (const float*)d_in[3];
  const float* b_ih1 = (const float*)d_in[4];
  const float* b_hh1 = (const float*)d_in[5];
  const float* w_ih2 = (const float*)d_in[6];
  const float* w_hh2 = (const float*)d_in[7];
  const float* b_ih2 = (const float*)d_in[8];
  const float* b_hh2 = (const float*)d_in[9];
  const float* w_lin = (const float*)d_in[10];
  const float* b_lin = (const float*)d_in[11];
  float* out = (float*)d_out;

  dim3 grid(B / 16);   // 512 blocks x 2 waves = 1024 waves
  dim3 block(128);
  hipLaunchKernelGGL(lstm_split8_kernel, grid, block, 0, stream,
                     input, w_ih1, w_hh1, b_ih1, b_hh1,
                     w_ih2, w_hh2, b_ih2, b_hh2, w_lin, b_lin, out);
}

// Round 8
// 356.975 us; speedup vs baseline: 1.8227x; 1.5238x over previous
//
#include <hip/hip_runtime.h>

// 2-layer LSTM (H=12), B=8192, T=1024 + 64 free-running steps.
// R14: PLACEMENT EXPERIMENT — 4-wave / 2-chain / 1-block-per-CU.
// R10-R13 counters: dur x VALUBusy = const (~204 us-chip) across ALL
// structures => issue work conserved, only stall varies. R13's iteration
// wall (8450 cy) equals bodyA+bodyB, not max(A,B): the block's two waves
// SERIALIZE on one SIMD. Fix attempt: 256 blocks x 256 threads = exactly one
// block per CU; 4 waves for 4 SIMDs -> allocator should spread 1 wave/SIMD.
// Waves {0,1} = chain A (cell1 producer, cell2 consumer), {2,3} = chain B.
// Per-chain code is byte-identical to R13 (8-step cadence, depth-16 FIFO,
// pre-issued x-loads, LDS y-partial flush-16). absmax canary: 2.441e-4.
// Outcome decides: ~300 us => spread worked (continue); ~850 us => waves of
// a workgroup co-reside per SIMD (revert to R13+trans-diet).
//
// Layout (harness-verified):
//   Row order R = 4*v + q; chunk c row (lane&15) -> v=4c+(m>>2), q=m&3.
//   K order k = 8*(u%4) + (u/4); B slot (g,j<3) = h_{4j+g} -> lane-local
//   D->B handoff; pads at j=3,7. Cell1 A zeros on h2 slots.
// Fragment maps (gfx950, HW-verified):
//   A[m=lane&15][k=8*(lane>>4)+j], B[k=8*(lane>>4)+j][n=lane&15],
//   D[row=4*(lane>>4)+reg][col=lane&15].

typedef _Float16 v8h  __attribute__((ext_vector_type(8)));
typedef _Float16 v4h  __attribute__((ext_vector_type(4)));
typedef float    v4f  __attribute__((ext_vector_type(4)));

constexpr int T   = 1024;
constexpr int FUT = 64;
constexpr int TT  = T + FUT;   // 1088 = 68*16 (flush-aligned, 8 | T)
constexpr int B   = 8192;

static __device__ __forceinline__ float fexp2(float x){ return __builtin_amdgcn_exp2f(x); }
static __device__ __forceinline__ float frcp (float x){ return __builtin_amdgcn_rcpf(x); }

__global__ __launch_bounds__(256) void lstm_quad_kernel(
    const float* __restrict__ input,
    const float* __restrict__ w_ih1, const float* __restrict__ w_hh1,
    const float* __restrict__ b_ih1, const float* __restrict__ b_hh1,
    const float* __restrict__ w_ih2, const float* __restrict__ w_hh2,
    const float* __restrict__ b_ih2, const float* __restrict__ b_hh2,
    const float* __restrict__ w_lin, const float* __restrict__ b_lin,
    float* __restrict__ out)
{
  const int tid  = threadIdx.x;
  const int wid  = tid >> 6;        // 0..3
  const int ch   = wid >> 1;        // chain within block (0/1)
  const int cw   = wid & 1;         // 0 = cell1 producer, 1 = cell2 consumer
  const int lane = tid & 63;
  const int g    = lane >> 4;       // unit residue group
  const int n    = lane & 15;       // element column
  const int e0   = blockIdx.x * 32 + ch * 16;

  const float L2E = 1.4426950408889634f;
  const float sc[4] = { -L2E, -L2E, 2.0f * L2E, -L2E };  // i,f,g,o prescale
  const float TWO_L2E = 2.885390081777927f;

  // ---- per-wave fragment set: cw0 = cell1, cw1 = cell2 -------------------
  v8h Aw[3]; v4f Cw[3];
  float wix[3][4];   // cw0 only: prescaled w_ih1
  float wl[3] = {0,0,0};
  {
    const int q = n & 3;
    #pragma unroll
    for (int c = 0; c < 3; ++c) {
      const int v   = 4 * c + (n >> 2);
      const int row = q * 12 + v;
      v8h a = {0,0,0,0,0,0,0,0};
      if (cw == 0) {
        #pragma unroll
        for (int j = 0; j < 3; ++j)
          a[j] = (_Float16)(sc[q] * w_hh1[row * 12 + (4 * j + g)]);
      } else {
        #pragma unroll
        for (int j = 0; j < 3; ++j) {
          const int u = 4 * j + g;
          a[j]     = (_Float16)(sc[q] * w_ih2[row * 12 + u]);  // h1 cols
          a[j + 4] = (_Float16)(sc[q] * w_hh2[row * 12 + u]);  // h2 cols
        }
      }
      Aw[c] = a;
    }
    #pragma unroll
    for (int c = 0; c < 3; ++c) {
      const int v = 4 * c + g;
      #pragma unroll
      for (int r = 0; r < 4; ++r) {
        if (cw == 0) {
          Cw[c][r]  = sc[r] * (b_ih1[r * 12 + v] + b_hh1[r * 12 + v]);
          wix[c][r] = sc[r] * w_ih1[r * 12 + v];
        } else {
          Cw[c][r]  = sc[r] * (b_ih2[r * 12 + v] + b_hh2[r * 12 + v]);
          wix[c][r] = 0.0f;
        }
      }
      if (cw == 1) wl[c] = w_lin[v];
    }
  }
  const float blin = b_lin[0];

  // ---- LDS per chain: h1 FIFO depth 16 (8 KiB) + y-partials (4 KiB) ------
  __shared__ v4h  fifo[2][16][64];
  __shared__ float yP[2][16][4][16];   // [ch][s%16][g][n]

  // ---- per-wave recurrent state (registers) ------------------------------
  float csw[3] = {0,0,0};
  v8h  Bw = {0,0,0,0,0,0,0,0};

  const float* xrow = input + (size_t)(e0 + n) * T;
  float*       yrow = out   + (size_t)(e0 + n) * TT;
  const float  xl   = xrow[T - 1];

  auto act3 = [&](const float (&G)[3][4], float (&h)[3]) {
    float Ai[3], Af[3], Eg[3], Ao[3];
    #pragma unroll
    for (int c = 0; c < 3; ++c) Ai[c] = fexp2(G[c][0]);
    #pragma unroll
    for (int c = 0; c < 3; ++c) Af[c] = fexp2(G[c][1]);
    #pragma unroll
    for (int c = 0; c < 3; ++c) Eg[c] = fexp2(G[c][2]);
    #pragma unroll
    for (int c = 0; c < 3; ++c) Ao[c] = fexp2(G[c][3]);
    float pfx[3], P[3], R[3], Nn[3], Ec[3], R2[3];
    #pragma unroll
    for (int c = 0; c < 3; ++c) { pfx[c] = 1.0f + Af[c]; P[c] = (1.0f + Ai[c]) * (1.0f + Eg[c]); }
    #pragma unroll
    for (int c = 0; c < 3; ++c) R[c]  = frcp(P[c] * pfx[c]);
    #pragma unroll
    for (int c = 0; c < 3; ++c) Nn[c] = fmaf(csw[c], P[c], (Eg[c] - 1.0f) * pfx[c]);
    #pragma unroll
    for (int c = 0; c < 3; ++c) csw[c] = Nn[c] * R[c];
    #pragma unroll
    for (int c = 0; c < 3; ++c) Ec[c] = fexp2(TWO_L2E * csw[c]);
    #pragma unroll
    for (int c = 0; c < 3; ++c) R2[c] = frcp((1.0f + Ao[c]) * (1.0f + Ec[c]));
    #pragma unroll
    for (int c = 0; c < 3; ++c) h[c] = (Ec[c] - 1.0f) * R2[c];
  };

  // producer: one cell1 step at time t; push h1(t) into chain FIFO slot t%16
  auto stepA = [&](int t, float x) {
    v4f D0 = __builtin_amdgcn_mfma_f32_16x16x32_f16(Aw[0], Bw, Cw[0], 0, 0, 0);
    v4f D1 = __builtin_amdgcn_mfma_f32_16x16x32_f16(Aw[1], Bw, Cw[1], 0, 0, 0);
    v4f D2 = __builtin_amdgcn_mfma_f32_16x16x32_f16(Aw[2], Bw, Cw[2], 0, 0, 0);
    float G[3][4], h[3];
    #pragma unroll
    for (int r = 0; r < 4; ++r) G[0][r] = fmaf(wix[0][r], x, D0[r]);
    #pragma unroll
    for (int r = 0; r < 4; ++r) G[1][r] = fmaf(wix[1][r], x, D1[r]);
    #pragma unroll
    for (int r = 0; r < 4; ++r) G[2][r] = fmaf(wix[2][r], x, D2[r]);
    act3(G, h);
    v4h pk;
    pk[0] = (_Float16)h[0]; pk[1] = (_Float16)h[1];
    pk[2] = (_Float16)h[2]; pk[3] = (_Float16)0.0f;
    fifo[ch][t & 15][lane] = pk;                 // fire-and-forget
    Bw[0] = pk[0]; Bw[1] = pk[1]; Bw[2] = pk[2];
  };

  // consumer: one cell2 step s with prefetched h1(s); y-partial -> LDS
  auto stepB = [&](v4h pf, int s) {
    Bw[0] = pf[0]; Bw[1] = pf[1]; Bw[2] = pf[2];
    v4f E0 = __builtin_amdgcn_mfma_f32_16x16x32_f16(Aw[0], Bw, Cw[0], 0, 0, 0);
    v4f E1 = __builtin_amdgcn_mfma_f32_16x16x32_f16(Aw[1], Bw, Cw[1], 0, 0, 0);
    v4f E2 = __builtin_amdgcn_mfma_f32_16x16x32_f16(Aw[2], Bw, Cw[2], 0, 0, 0);
    float G[3][4], h[3];
    #pragma unroll
    for (int r = 0; r < 4; ++r) G[0][r] = E0[r];
    #pragma unroll
    for (int r = 0; r < 4; ++r) G[1][r] = E1[r];
    #pragma unroll
    for (int r = 0; r < 4; ++r) G[2][r] = E2[r];
    act3(G, h);
    Bw[4] = (_Float16)h[0]; Bw[5] = (_Float16)h[1]; Bw[6] = (_Float16)h[2];
    float yp = h[0] * wl[0];
    yp = fmaf(h[1], wl[1], yp);
    yp = fmaf(h[2], wl[2], yp);
    yP[ch][s & 15][g][n] = yp;                   // fire-and-forget
  };

  // consumer: reduce + store one 16-step batch (own writes, same-wave order)
  auto flush = [&](int sbase) {
    const int tq = lane >> 4;
    float ys[4];
    #pragma unroll
    for (int ii = 0; ii < 4; ++ii) {
      const int j = 4 * tq + ii;
      ys[ii] = (yP[ch][j][0][n] + yP[ch][j][1][n])
             + (yP[ch][j][2][n] + yP[ch][j][3][n]) + blin;
    }
    *reinterpret_cast<float4*>(yrow + sbase + 4 * tq) =
        make_float4(ys[0], ys[1], ys[2], ys[3]);
  };

  // Prologue x: steps 0..7 (direct load; waits once before the loop).
  float4 xc0 = make_float4(0,0,0,0), xc1 = xc0;
  if (cw == 0) {
    xc0 = *reinterpret_cast<const float4*>(xrow);
    xc1 = *reinterpret_cast<const float4*>(xrow + 4);
  }

  for (int kb = 0; kb <= TT; kb += 8) {
    if (cw == 0) {
      if (kb < TT) {
        // Issue NEXT iteration's x-loads FIRST so the barrier vmcnt drain
        // is free.
        float4 xn0, xn1;
        const int nb = kb + 8;
        if (nb < T) {
          xn0 = *reinterpret_cast<const float4*>(xrow + nb);
          xn1 = *reinterpret_cast<const float4*>(xrow + nb + 4);
        } else {
          xn0 = make_float4(xl, xl, xl, xl);
          xn1 = xn0;
        }
        stepA(kb + 0, xc0.x);
        stepA(kb + 1, xc0.y);
        stepA(kb + 2, xc0.z);
        stepA(kb + 3, xc0.w);
        stepA(kb + 4, xc1.x);
        stepA(kb + 5, xc1.y);
        stepA(kb + 6, xc1.z);
        stepA(kb + 7, xc1.w);
        xc0 = xn0; xc1 = xn1;
      }
    } else {
      if (kb >= 8) {
        const int s0 = kb - 8;
        // all 8 slots written one barrier ago; disjoint halves mod 16
        v4h p0 = fifo[ch][(s0 + 0) & 15][lane];
        v4h p1 = fifo[ch][(s0 + 1) & 15][lane];
        v4h p2 = fifo[ch][(s0 + 2) & 15][lane];
        v4h p3 = fifo[ch][(s0 + 3) & 15][lane];
        v4h p4 = fifo[ch][(s0 + 4) & 15][lane];
        v4h p5 = fifo[ch][(s0 + 5) & 15][lane];
        v4h p6 = fifo[ch][(s0 + 6) & 15][lane];
        v4h p7 = fifo[ch][(s0 + 7) & 15][lane];
        stepB(p0, s0 + 0);
        stepB(p1, s0 + 1);
        stepB(p2, s0 + 2);
        stepB(p3, s0 + 3);
        stepB(p4, s0 + 4);
        stepB(p5, s0 + 5);
        stepB(p6, s0 + 6);
        stepB(p7, s0 + 7);
        if ((kb & 15) == 0) flush(kb - 16);   // steps kb-16..kb-1 all done
      }
    }
    __syncthreads();
  }
}

extern "C" void kernel_launch(void* const* d_in, const int* in_sizes, int n_in,
                              void* d_out, int out_size, void* d_ws, size_t ws_size,
                              hipStream_t stream) {
  const float* input = (const float*)d_in[0];
  const float* w_ih1 = (const float*)d_in[2];
  const float* w_hh1 = (const float*)d_in[3];
  const float* b_ih1 = (const float*)d_in[4];
  const float* b_hh1 = (const float*)d_in[5];
  const float* w_ih2 = (const float*)d_in[6];
  const float* w_hh2 = (const float*)d_in[7];
  const float* b_ih2 = (const float*)d_in[8];
  const float* b_hh2 = (const float*)d_in[9];
  const float* w_lin = (const float*)d_in[10];
  const float* b_lin = (const float*)d_in[11];
  float* out = (float*)d_out;

  dim3 grid(B / 32);   // 256 blocks x 4 waves = 1024 waves, 1 block per CU
  dim3 block(256);
  hipLaunchKernelGGL(lstm_quad_kernel, grid, block, 0, stream,
                     input, w_ih1, w_hh1, b_ih1, b_hh1,
                     w_ih2, w_hh2, b_ih2, b_hh2, w_lin, b_lin, out);
}